// Round 4
// baseline (179.988 us; speedup 1.0000x reference)
//
#include <hip/hip_runtime.h>

// Problem constants (from reference: M, B, D = 32, 64, 8192)
#define Mh 32
#define Bh 64
#define Dh 8192
#define KCH 256           // K-range per workgroup in gram kernel
#define NCH (Dh / KCH)    // 32 k-chunks -> 2048 blocks
#define CCH 8             // d-chunks for combine

// Workspace layout (float offsets). Base ~545 KB + optional 16 MB slab.
#define OFF_WSY 0                       // [64][32][32]  Wsy[i][j] = s_i . y_j
#define OFF_WYY (64 * 1024)             // [64][32][32]  Wyy[i][j] = y_i . y_j
#define OFF_VS  (2 * 64 * 1024)         // [64][32]      vs[i] = s_i . frc
#define OFF_VY  (OFF_VS + 64 * 32)      // [64][32]      vy[i] = y_i . frc
#define OFF_CY  (OFF_VY + 64 * 32)      // [64][32]      g * a_i
#define OFF_CS  (OFF_CY + 64 * 32)      // [64][32]      b_i - a_i
#define OFF_G   (OFF_CS + 64 * 32)      // [64]          g per batch
#define WS_ZERO_FLOATS OFF_CY           // atomic-path zero region
// Gram partial slabs (slab path): PSY[ch][b][1024], PYY[ch][b][1024]
#define OFF_PART (OFF_G + 64)
#define PART_FLOATS (NCH * 64 * 1024)   // per matrix: 8 MB

typedef __attribute__((ext_vector_type(4)))  __bf16 bf16x4;
typedef __attribute__((ext_vector_type(8)))  __bf16 bf16x8;
typedef __attribute__((ext_vector_type(16))) float  f32x16;

// fp32 -> bf16 hi/lo split: x ~= hi + lo with |err| ~ 2^-18 |x|
__device__ __forceinline__ void split4(const float4 v, bf16x4& h, bf16x4& l)
{
    h[0] = (__bf16)v.x; h[1] = (__bf16)v.y; h[2] = (__bf16)v.z; h[3] = (__bf16)v.w;
    l[0] = (__bf16)(v.x - (float)h[0]);
    l[1] = (__bf16)(v.y - (float)h[1]);
    l[2] = (__bf16)(v.z - (float)h[2]);
    l[3] = (__bf16)(v.w - (float)h[3]);
}

// ---------------------------------------------------------------------------
// Kernel A: batched Gram matrices via bf16-split MFMA.
// grid = 64 b x 32 k-chunks, 256 threads (4 waves).
// Round-3 evidence: MFMA loop is cheap (MfmaUtil 4.3%, VALU 11%) but the
// kernel sat at 51 us with all pipes idle; WRITE_SIZE == 4.3M atomics x 4B
// -> every Gram atomic hits memory-side; 4.3M/51us = 84e9 atomics/s ~= the
// contended-fp32-atomic fabric ceiling. SLAB=1 replaces the 2048 atomics
// per block with plain float4 stores to a per-(ch,b) slab; reduce_kernel
// sums the 32 slabs. SLAB=0 is the atomic fallback when ws is too small.
// NO min-waves launch_bounds clamp (round-1: clamp -> spill -> 987 us).
// ---------------------------------------------------------------------------
template <int SLAB>
__global__ __launch_bounds__(256) void gram_kernel(
    const float* __restrict__ s, const float* __restrict__ y,
    const float* __restrict__ frc, float* __restrict__ ws)
{
    // [buf][mat: sH,sL,yH,yL][32 rows * 64 k] bf16, XOR-8 swizzled = 32 KB
    __shared__ __align__(16) __bf16 lds[2][4][2048];

    const int b  = blockIdx.x & 63;
    const int ch = blockIdx.x >> 6;
    const int k0 = ch * KCH;
    const int t  = threadIdx.x;
    const int w  = t >> 6;        // wave 0..3 -> k-slice w of each 64-k stage
    const int l  = t & 63;

    f32x16 accSY = {};            // partial Wsy (this wave's k subset)
    f32x16 accYY = {};            // partial Wyy
    float avs0 = 0.f, avs1 = 0.f, avy0 = 0.f, avy1 = 0.f;

    // staging: thread t covers rows i0 (0..15) and i1 (16..31), 4 k's each
    const int i0 = t >> 4, i1 = i0 + 16, k4 = t & 15;
    const int e0 = i0 * 64 + ((k4 << 2) ^ ((i0 & 7) << 3));
    const int e1 = i1 * 64 + ((k4 << 2) ^ ((i1 & 7) << 3));

    const float* sp0 = s + ((size_t)i0 * Bh + b) * Dh + k0 + (k4 << 2);
    const float* yp0 = y + ((size_t)i0 * Bh + b) * Dh + k0 + (k4 << 2);
    const float* sp1 = s + ((size_t)i1 * Bh + b) * Dh + k0 + (k4 << 2);
    const float* yp1 = y + ((size_t)i1 * Bh + b) * Dh + k0 + (k4 << 2);
    const float* fp  = frc + (size_t)b * Dh + k0 + (k4 << 2);

    // prefetch stage 0
    float4 sv0 = *(const float4*)sp0;
    float4 yv0 = *(const float4*)yp0;
    float4 sv1 = *(const float4*)sp1;
    float4 yv1 = *(const float4*)yp1;
    float4 fv  = *(const float4*)fp;

    // MFMA fragment address: lane l reads row (l&31), 8 bf16 at k-offset
    // w*16 + 8*(l>>5), with the same XOR swizzle (16B-granule aligned).
    const int row = l & 31;
    const int fo  = (w << 4) + ((l >> 5) << 3);
    const int fe  = row * 64 + (fo ^ ((row & 7) << 3));

    int p = 0;
    const int nst = KCH / 64;   // 4 stages
    for (int st = 0; st < nst; ++st) {
        // convert + write prefetched stage into buffer p
        bf16x4 h, lo;
        split4(sv0, h, lo); *(bf16x4*)&lds[p][0][e0] = h; *(bf16x4*)&lds[p][1][e0] = lo;
        split4(yv0, h, lo); *(bf16x4*)&lds[p][2][e0] = h; *(bf16x4*)&lds[p][3][e0] = lo;
        split4(sv1, h, lo); *(bf16x4*)&lds[p][0][e1] = h; *(bf16x4*)&lds[p][1][e1] = lo;
        split4(yv1, h, lo); *(bf16x4*)&lds[p][2][e1] = h; *(bf16x4*)&lds[p][3][e1] = lo;

        // frc dot-product partials on the exact fp32 values (no bf16 loss)
        avs0 += sv0.x * fv.x + sv0.y * fv.y + sv0.z * fv.z + sv0.w * fv.w;
        avy0 += yv0.x * fv.x + yv0.y * fv.y + yv0.z * fv.z + yv0.w * fv.w;
        avs1 += sv1.x * fv.x + sv1.y * fv.y + sv1.z * fv.z + sv1.w * fv.w;
        avy1 += yv1.x * fv.x + yv1.y * fv.y + yv1.z * fv.z + yv1.w * fv.w;

        // issue next stage's global loads; latency hides under MFMA phase
        if (st + 1 < nst) {
            const int o = (st + 1) * 64;
            sv0 = *(const float4*)(sp0 + o);
            yv0 = *(const float4*)(yp0 + o);
            sv1 = *(const float4*)(sp1 + o);
            yv1 = *(const float4*)(yp1 + o);
            fv  = *(const float4*)(fp + o);
        }
        __syncthreads();

        // wave w: its 16-k slice of this stage, 4 frag reads + 6 MFMAs
        const bf16x8 aSH = *(const bf16x8*)&lds[p][0][fe];
        const bf16x8 aSL = *(const bf16x8*)&lds[p][1][fe];
        const bf16x8 aYH = *(const bf16x8*)&lds[p][2][fe];
        const bf16x8 aYL = *(const bf16x8*)&lds[p][3][fe];
        accSY = __builtin_amdgcn_mfma_f32_32x32x16_bf16(aSH, aYH, accSY, 0, 0, 0);
        accYY = __builtin_amdgcn_mfma_f32_32x32x16_bf16(aYH, aYH, accYY, 0, 0, 0);
        accSY = __builtin_amdgcn_mfma_f32_32x32x16_bf16(aSH, aYL, accSY, 0, 0, 0);
        accYY = __builtin_amdgcn_mfma_f32_32x32x16_bf16(aYH, aYL, accYY, 0, 0, 0);
        accSY = __builtin_amdgcn_mfma_f32_32x32x16_bf16(aSL, aYH, accSY, 0, 0, 0);
        accYY = __builtin_amdgcn_mfma_f32_32x32x16_bf16(aYL, aYH, accYY, 0, 0, 0);
        p ^= 1;
    }

    // vs/vy: butterfly over the 16 threads sharing each row, then atomics
    // (131K atomics total across the grid -- negligible)
    #pragma unroll
    for (int m = 1; m < 16; m <<= 1) {
        avs0 += __shfl_xor(avs0, m);
        avs1 += __shfl_xor(avs1, m);
        avy0 += __shfl_xor(avy0, m);
        avy1 += __shfl_xor(avy1, m);
    }
    const int g16 = t & 15;
    if      (g16 == 0) unsafeAtomicAdd(&ws[OFF_VS + b * 32 + i0], avs0);
    else if (g16 == 1) unsafeAtomicAdd(&ws[OFF_VS + b * 32 + i1], avs1);
    else if (g16 == 2) unsafeAtomicAdd(&ws[OFF_VY + b * 32 + i0], avy0);
    else if (g16 == 3) unsafeAtomicAdd(&ws[OFF_VY + b * 32 + i1], avy1);

    // cross-wave reduction of the 32x32 partials through the freed LDS
    __syncthreads();
    float* RS = (float*)&lds[0][0][0];   // 4 waves x 1024 floats (Wsy)
    float* RY = RS + 4096;               // 4 waves x 1024 floats (Wyy)
    #pragma unroll
    for (int r = 0; r < 16; ++r) {
        const int i = (r & 3) + ((r >> 2) << 3) + ((l >> 5) << 2);
        const int j = l & 31;
        RS[w * 1024 + i * 32 + j] = accSY[r];
        RY[w * 1024 + i * 32 + j] = accYY[r];
    }
    __syncthreads();

    if (SLAB) {
        // plain float4 stores to this block's private slab
        float* PS = ws + OFF_PART + ((size_t)(ch * 64 + b)) * 1024;
        float* PY = ws + OFF_PART + PART_FLOATS + ((size_t)(ch * 64 + b)) * 1024;
        const int e4 = t << 2;
        float4 o0, o1;
        const float4 a0 = *(const float4*)&RS[e4];
        const float4 a1 = *(const float4*)&RS[1024 + e4];
        const float4 a2 = *(const float4*)&RS[2048 + e4];
        const float4 a3 = *(const float4*)&RS[3072 + e4];
        o0.x = a0.x + a1.x + a2.x + a3.x;  o0.y = a0.y + a1.y + a2.y + a3.y;
        o0.z = a0.z + a1.z + a2.z + a3.z;  o0.w = a0.w + a1.w + a2.w + a3.w;
        *(float4*)&PS[e4] = o0;
        const float4 c0 = *(const float4*)&RY[e4];
        const float4 c1 = *(const float4*)&RY[1024 + e4];
        const float4 c2 = *(const float4*)&RY[2048 + e4];
        const float4 c3 = *(const float4*)&RY[3072 + e4];
        o1.x = c0.x + c1.x + c2.x + c3.x;  o1.y = c0.y + c1.y + c2.y + c3.y;
        o1.z = c0.z + c1.z + c2.z + c3.z;  o1.w = c0.w + c1.w + c2.w + c3.w;
        *(float4*)&PY[e4] = o1;
    } else {
        float* WSY = ws + OFF_WSY + b * 1024;
        float* WYY = ws + OFF_WYY + b * 1024;
        for (int e = t; e < 1024; e += 256) {
            unsafeAtomicAdd(&WSY[e], RS[e] + RS[1024 + e] + RS[2048 + e] + RS[3072 + e]);
            unsafeAtomicAdd(&WYY[e], RY[e] + RY[1024 + e] + RY[2048 + e] + RY[3072 + e]);
        }
    }
}

// ---------------------------------------------------------------------------
// Kernel A2 (slab path): sum the 32 chunk-partials into WSY / WYY.
// grid = 128 blocks (64 b x 2 matrices) x 256 threads; each thread owns one
// float4 of the output and does 32 coalesced slab loads + 1 store.
// ---------------------------------------------------------------------------
__global__ __launch_bounds__(256) void reduce_kernel(float* __restrict__ ws)
{
    const int b = blockIdx.x >> 1;
    const int m = blockIdx.x & 1;     // 0: Wsy, 1: Wyy
    const int e4 = threadIdx.x << 2;

    const float* P = ws + OFF_PART + (size_t)m * PART_FLOATS;
    float4 acc = make_float4(0.f, 0.f, 0.f, 0.f);
    #pragma unroll
    for (int ch = 0; ch < NCH; ++ch) {
        const float4 v = *(const float4*)&P[((size_t)(ch * 64 + b)) * 1024 + e4];
        acc.x += v.x; acc.y += v.y; acc.z += v.z; acc.w += v.w;
    }
    float* W = ws + (m ? OFF_WYY : OFF_WSY) + b * 1024;
    *(float4*)&W[e4] = acc;
}

// ---------------------------------------------------------------------------
// Kernel B: per-b M=32 recursion on the Gram matrices, f64, one wave per b.
// Lane i owns row i (and column i) of Wsy and row i of Wyy. (unchanged)
// ---------------------------------------------------------------------------
__global__ __launch_bounds__(64) void recur_kernel(float* __restrict__ ws)
{
    const int b    = blockIdx.x;
    const int lane = threadIdx.x;
    const int i    = lane & 31;   // lanes 32..63 mirror 0..31 (writes guarded)

    const float* WSY = ws + OFF_WSY + b * 1024;
    const float* WYY = ws + OFF_WYY + b * 1024;

    float row_sy[32], col_sy[32], row_yy[32];
    #pragma unroll
    for (int j = 0; j < 32; ++j) {
        row_sy[j] = WSY[i * 32 + j];   // s_i . y_j
        col_sy[j] = WSY[j * 32 + i];   // s_j . y_i
        row_yy[j] = WYY[i * 32 + j];   // y_i . y_j
    }

    const double r = 1.0 / (double)row_sy[i];          // 1/(s_i.y_i)
    double acc = -(double)ws[OFF_VS + b * 32 + i];     // s_i.q0 running
    double a_val = 0.0;
    #pragma unroll
    for (int j = 31; j >= 0; --j) {                    // backward scan
        const double aj = __shfl(r, j) * __shfl(acc, j);
        if (i == j) a_val = aj;
        if (i < j)  acc -= aj * (double)row_sy[j];
    }

    const double g = (double)WSY[31 * 32 + 31] / (double)WYY[31 * 32 + 31];

    double u = -(double)ws[OFF_VY + b * 32 + i];       // y_i.q_f0 / g
    #pragma unroll
    for (int j = 0; j < 32; ++j)
        u -= __shfl(a_val, j) * (double)row_yy[j];
    u *= g;

    double tt = u;
    double b_val = 0.0;
    #pragma unroll
    for (int j = 0; j < 32; ++j) {                     // forward scan
        const double bj = __shfl(r, j) * __shfl(tt, j);
        if (i == j) b_val = bj;
        const double dj = __shfl(a_val, j) - bj;
        if (i > j) tt += dj * (double)col_sy[j];
    }

    if (lane < 32) {
        ws[OFF_CY + b * 32 + i] = (float)(g * a_val);
        ws[OFF_CS + b * 32 + i] = (float)(b_val - a_val);
    }
    if (lane == 0) ws[OFF_G + b] = (float)g;
}

// ---------------------------------------------------------------------------
// Kernel C: out[b,d] = g*frc[b,d] + sum_i cy[i]*y[i,b,d] + cs[i]*s[i,b,d]
// grid = 64 b x 8 d-chunks, 1024 threads (16 waves). i-sum split 4-way
// across thread quarters (8 i's + frc for q==0), LDS tree reduce at end.
// (unchanged this round -- waiting for counters once gram shrinks)
// ---------------------------------------------------------------------------
__global__ __launch_bounds__(1024) void combine_kernel(
    const float* __restrict__ s, const float* __restrict__ y,
    const float* __restrict__ frc, const float* __restrict__ ws,
    float* __restrict__ out)
{
    __shared__ float cy[32], cs[32];
    __shared__ float4 red[3][256];
    const int b  = blockIdx.x & 63;
    const int ch = blockIdx.x >> 6;
    const int t  = threadIdx.x;
    const int q  = t >> 8;          // quarter 0..3: i in [8q, 8q+8)
    const int tt = t & 255;
    if (t < 32) { cy[t] = ws[OFF_CY + b * 32 + t]; cs[t] = ws[OFF_CS + b * 32 + t]; }
    __syncthreads();

    const int d = ch * 1024 + (tt << 2);
    float4 acc = make_float4(0.f, 0.f, 0.f, 0.f);
    if (q == 0) {
        const float g = ws[OFF_G + b];
        const float4 fv = *(const float4*)(frc + (size_t)b * Dh + d);
        acc.x = g * fv.x; acc.y = g * fv.y; acc.z = g * fv.z; acc.w = g * fv.w;
    }
    const int ib = q << 3;
    #pragma unroll
    for (int i2 = 0; i2 < 8; ++i2) {
        const int i = ib + i2;
        const float4 yv = *(const float4*)(y + ((size_t)i * Bh + b) * Dh + d);
        const float4 sv = *(const float4*)(s + ((size_t)i * Bh + b) * Dh + d);
        const float a1 = cy[i], a2 = cs[i];
        acc.x += a1 * yv.x + a2 * sv.x;
        acc.y += a1 * yv.y + a2 * sv.y;
        acc.z += a1 * yv.z + a2 * sv.z;
        acc.w += a1 * yv.w + a2 * sv.w;
    }
    if (q) red[q - 1][tt] = acc;
    __syncthreads();
    if (q == 0) {
        const float4 r0 = red[0][tt], r1 = red[1][tt], r2 = red[2][tt];
        acc.x += r0.x + r1.x + r2.x;
        acc.y += r0.y + r1.y + r2.y;
        acc.z += r0.z + r1.z + r2.z;
        acc.w += r0.w + r1.w + r2.w;
        *(float4*)(out + (size_t)b * Dh + d) = acc;
    }
}

extern "C" void kernel_launch(void* const* d_in, const int* in_sizes, int n_in,
                              void* d_out, int out_size, void* d_ws, size_t ws_size,
                              hipStream_t stream)
{
    const float* s   = (const float*)d_in[0];
    const float* y   = (const float*)d_in[1];
    const float* frc = (const float*)d_in[2];
    float* out = (float*)d_out;
    float* ws  = (float*)d_ws;

    const size_t need = ((size_t)OFF_PART + 2 * (size_t)PART_FLOATS) * sizeof(float);
    if (ws_size >= need) {
        // slab path: only vs/vy use atomics -> zero just that 16 KB
        hipMemsetAsync((char*)d_ws + (size_t)OFF_VS * sizeof(float), 0,
                       (size_t)(OFF_CY - OFF_VS) * sizeof(float), stream);
        gram_kernel<1><<<dim3(Bh * NCH), dim3(256), 0, stream>>>(s, y, frc, ws);
        reduce_kernel<<<dim3(128), dim3(256), 0, stream>>>(ws);
    } else {
        // atomic fallback (round-3 behavior)
        hipMemsetAsync(d_ws, 0, (size_t)WS_ZERO_FLOATS * sizeof(float), stream);
        gram_kernel<0><<<dim3(Bh * NCH), dim3(256), 0, stream>>>(s, y, frc, ws);
    }
    recur_kernel<<<dim3(Bh), dim3(64), 0, stream>>>(ws);
    combine_kernel<<<dim3(Bh * CCH), dim3(1024), 0, stream>>>(s, y, frc, ws, out);
}

// Round 5
// 179.436 us; speedup vs baseline: 1.0031x; 1.0031x over previous
//
#include <hip/hip_runtime.h>

// Problem constants (from reference: M, B, D = 32, 64, 8192)
#define Mh 32
#define Bh 64
#define Dh 8192
#define KCH 256           // K-range per workgroup in gram kernel
#define NCH (Dh / KCH)    // 32 k-chunks -> 2048 blocks
#define CCH 8             // d-chunks for combine

// Workspace layout (float offsets). Base ~545 KB + optional 16 MB slab.
#define OFF_WSY 0                       // [64][32][32]  (atomic-fallback only)
#define OFF_WYY (64 * 1024)             // [64][32][32]  (atomic-fallback only)
#define OFF_VS  (2 * 64 * 1024)         // [64][32]      vs[i] = s_i . frc
#define OFF_VY  (OFF_VS + 64 * 32)      // [64][32]      vy[i] = y_i . frc
#define OFF_CY  (OFF_VY + 64 * 32)      // [64][32]      g * a_i
#define OFF_CS  (OFF_CY + 64 * 32)      // [64][32]      b_i - a_i
#define OFF_G   (OFF_CS + 64 * 32)      // [64]          g per batch
#define WS_ZERO_FLOATS OFF_CY           // atomic-path zero region
// Gram partial slabs (slab path): PSY[ch][b][1024], PYY[ch][b][1024]
#define OFF_PART (OFF_G + 64)
#define PART_FLOATS (NCH * 64 * 1024)   // per matrix: 8 MB

typedef __attribute__((ext_vector_type(8)))  __bf16 bf16x8;
typedef __attribute__((ext_vector_type(16))) float  f32x16;

typedef __attribute__((address_space(1))) const unsigned int gu32;
typedef __attribute__((address_space(3))) unsigned int lu32;

// fp32x8 -> bf16 hi/lo split: x ~= hi + lo with |err| ~ 2^-18 |x|
__device__ __forceinline__ void split8(const float4 a, const float4 b,
                                       bf16x8& h, bf16x8& lo)
{
    const float x[8] = {a.x, a.y, a.z, a.w, b.x, b.y, b.z, b.w};
    #pragma unroll
    for (int e = 0; e < 8; ++e) {
        h[e]  = (__bf16)x[e];
        lo[e] = (__bf16)(x[e] - (float)h[e]);
    }
}

// ---------------------------------------------------------------------------
// Kernel A: batched Gram matrices via bf16-split MFMA, burst-loaded.
// grid = 64 b x 32 k-chunks, 256 threads (4 waves).
// Round-4 evidence: slab-vs-atomic was a null (47 vs 51 us) -> the read side
// limits. Old structure was 1-stage-deep: each __syncthreads drains
// vmcnt(0), serializing one HBM round trip per 64-k stage, and each row is
// requested 256B at a time. New structure: issue ALL 16 global_load_lds ops
// (whole 256-k chunk, s+y, fp32) BEFORE the first barrier -> the single
// drain waits for one 64KB burst (full MLP, 1KB/row in flight), then the
// 4-stage MFMA loop runs with NO barriers (LDS is read-only until epilogue).
// bf16 hi/lo split moved to fragment-read time (same fp32 -> same math).
// Swizzle per rule 21: linear LDS dest + XOR(row&15) pre-swizzled GLOBAL
// source + same XOR on LDS reads (involution). 8 lanes/bank-quad = optimal.
// NO min-waves launch_bounds clamp (round-1: clamp -> spill -> 987 us).
// ---------------------------------------------------------------------------
template <int SLAB>
__global__ __launch_bounds__(256) void gram_kernel(
    const float* __restrict__ s, const float* __restrict__ y,
    const float* __restrict__ frc, float* __restrict__ ws)
{
    __shared__ __align__(16) float sF[4][32][64];   // fp32, slot-swizzled, 32 KB
    __shared__ __align__(16) float yF[4][32][64];   // 32 KB

    const int b  = blockIdx.x & 63;
    const int ch = blockIdx.x >> 6;
    const int k0 = ch * KCH;
    const int t  = threadIdx.x;
    const int w  = t >> 6;        // wave 0..3
    const int l  = t & 63;

    // ---- burst: 16 global_load_lds per thread, all before the barrier ----
    // op (w, st, o): rows rbase..rbase+3 (rbase = 8w+4o), lane l -> row
    // rbase+(l>>4), LDS slot l&15 holds global granule (l&15)^(row&15).
    {
        const int lr  = l >> 4;
        const int s16 = l & 15;
        #pragma unroll
        for (int st = 0; st < 4; ++st) {
            #pragma unroll
            for (int o = 0; o < 2; ++o) {
                const int rbase = (w << 3) + (o << 2);
                const int i = rbase + lr;
                const int g = s16 ^ (i & 15);
                const size_t go = ((size_t)i * Bh + b) * Dh + k0 + st * 64 + (g << 2);
                __builtin_amdgcn_global_load_lds((gu32*)(s + go),
                                                 (lu32*)&sF[st][rbase][0], 16, 0, 0);
                __builtin_amdgcn_global_load_lds((gu32*)(y + go),
                                                 (lu32*)&yF[st][rbase][0], 16, 0, 0);
            }
        }
    }

    // frc stays in per-thread registers (vec-dots remain exact fp32)
    const int i0 = t >> 4, i1 = i0 + 16, k4 = t & 15;
    const float* fp = frc + (size_t)b * Dh + k0 + (k4 << 2);
    float4 fv[4];
    #pragma unroll
    for (int st = 0; st < 4; ++st) fv[st] = *(const float4*)(fp + st * 64);

    __syncthreads();   // ONE drain for the whole 64 KB burst

    f32x16 accSY = {};
    f32x16 accYY = {};
    float avs0 = 0.f, avs1 = 0.f, avy0 = 0.f, avy1 = 0.f;

    // MFMA fragment: lane l = row (l&31), k-window granules g0, g0+1
    const int row = l & 31;
    const int g0  = (w << 2) + ((l >> 5) << 1);
    const int rx  = row & 15;
    const int x0  = i0 & 15, x1 = i1 & 15;

    #pragma unroll
    for (int st = 0; st < 4; ++st) {
        const float4 sa = *(const float4*)&sF[st][row][(g0 ^ rx) << 2];
        const float4 sb = *(const float4*)&sF[st][row][((g0 + 1) ^ rx) << 2];
        const float4 ya = *(const float4*)&yF[st][row][(g0 ^ rx) << 2];
        const float4 yb = *(const float4*)&yF[st][row][((g0 + 1) ^ rx) << 2];
        bf16x8 aSH, aSL, aYH, aYL;
        split8(sa, sb, aSH, aSL);
        split8(ya, yb, aYH, aYL);
        accSY = __builtin_amdgcn_mfma_f32_32x32x16_bf16(aSH, aYH, accSY, 0, 0, 0);
        accYY = __builtin_amdgcn_mfma_f32_32x32x16_bf16(aYH, aYH, accYY, 0, 0, 0);
        accSY = __builtin_amdgcn_mfma_f32_32x32x16_bf16(aSH, aYL, accSY, 0, 0, 0);
        accYY = __builtin_amdgcn_mfma_f32_32x32x16_bf16(aYH, aYL, accYY, 0, 0, 0);
        accSY = __builtin_amdgcn_mfma_f32_32x32x16_bf16(aSL, aYH, accSY, 0, 0, 0);
        accYY = __builtin_amdgcn_mfma_f32_32x32x16_bf16(aYL, aYH, accYY, 0, 0, 0);

        // exact-fp32 frc dot partials, read back from the fp32 tiles
        const float4 s0v = *(const float4*)&sF[st][i0][(k4 ^ x0) << 2];
        const float4 y0v = *(const float4*)&yF[st][i0][(k4 ^ x0) << 2];
        const float4 s1v = *(const float4*)&sF[st][i1][(k4 ^ x1) << 2];
        const float4 y1v = *(const float4*)&yF[st][i1][(k4 ^ x1) << 2];
        const float4 f = fv[st];
        avs0 += s0v.x * f.x + s0v.y * f.y + s0v.z * f.z + s0v.w * f.w;
        avy0 += y0v.x * f.x + y0v.y * f.y + y0v.z * f.z + y0v.w * f.w;
        avs1 += s1v.x * f.x + s1v.y * f.y + s1v.z * f.z + s1v.w * f.w;
        avy1 += y1v.x * f.x + y1v.y * f.y + y1v.z * f.z + y1v.w * f.w;
    }

    // vs/vy: butterfly over the 16 threads sharing each row, then atomics
    #pragma unroll
    for (int m = 1; m < 16; m <<= 1) {
        avs0 += __shfl_xor(avs0, m);
        avs1 += __shfl_xor(avs1, m);
        avy0 += __shfl_xor(avy0, m);
        avy1 += __shfl_xor(avy1, m);
    }
    const int g16 = t & 15;
    if      (g16 == 0) unsafeAtomicAdd(&ws[OFF_VS + b * 32 + i0], avs0);
    else if (g16 == 1) unsafeAtomicAdd(&ws[OFF_VS + b * 32 + i1], avs1);
    else if (g16 == 2) unsafeAtomicAdd(&ws[OFF_VY + b * 32 + i0], avy0);
    else if (g16 == 3) unsafeAtomicAdd(&ws[OFF_VY + b * 32 + i1], avy1);

    // cross-wave reduction of the 32x32 partials through the freed LDS
    __syncthreads();
    float* RS = (float*)&sF[0][0][0];   // 4 waves x 1024 floats (Wsy)
    float* RY = (float*)&yF[0][0][0];   // 4 waves x 1024 floats (Wyy)
    #pragma unroll
    for (int r = 0; r < 16; ++r) {
        const int i = (r & 3) + ((r >> 2) << 3) + ((l >> 5) << 2);
        const int j = l & 31;
        RS[w * 1024 + i * 32 + j] = accSY[r];
        RY[w * 1024 + i * 32 + j] = accYY[r];
    }
    __syncthreads();

    if (SLAB) {
        float* PS = ws + OFF_PART + ((size_t)(ch * 64 + b)) * 1024;
        float* PY = ws + OFF_PART + PART_FLOATS + ((size_t)(ch * 64 + b)) * 1024;
        const int e4 = t << 2;
        float4 o0, o1;
        const float4 a0 = *(const float4*)&RS[e4];
        const float4 a1 = *(const float4*)&RS[1024 + e4];
        const float4 a2 = *(const float4*)&RS[2048 + e4];
        const float4 a3 = *(const float4*)&RS[3072 + e4];
        o0.x = a0.x + a1.x + a2.x + a3.x;  o0.y = a0.y + a1.y + a2.y + a3.y;
        o0.z = a0.z + a1.z + a2.z + a3.z;  o0.w = a0.w + a1.w + a2.w + a3.w;
        *(float4*)&PS[e4] = o0;
        const float4 c0 = *(const float4*)&RY[e4];
        const float4 c1 = *(const float4*)&RY[1024 + e4];
        const float4 c2 = *(const float4*)&RY[2048 + e4];
        const float4 c3 = *(const float4*)&RY[3072 + e4];
        o1.x = c0.x + c1.x + c2.x + c3.x;  o1.y = c0.y + c1.y + c2.y + c3.y;
        o1.z = c0.z + c1.z + c2.z + c3.z;  o1.w = c0.w + c1.w + c2.w + c3.w;
        *(float4*)&PY[e4] = o1;
    } else {
        float* WSY = ws + OFF_WSY + b * 1024;
        float* WYY = ws + OFF_WYY + b * 1024;
        for (int e = t; e < 1024; e += 256) {
            unsafeAtomicAdd(&WSY[e], RS[e] + RS[1024 + e] + RS[2048 + e] + RS[3072 + e]);
            unsafeAtomicAdd(&WYY[e], RY[e] + RY[1024 + e] + RY[2048 + e] + RY[3072 + e]);
        }
    }
}

// ---------------------------------------------------------------------------
// Kernel B (fused): slab-reduce the Gram partials into LDS, then run the
// per-b M=32 f64 recursion from LDS. grid = 64 blocks x 256 threads.
// Replaces reduce_kernel + recur_kernel (one fewer launch; no WSY round
// trip through global). SLAB=0 fallback reads the atomically-built ws Gram.
// ---------------------------------------------------------------------------
template <int SLAB>
__global__ __launch_bounds__(256) void recur_kernel(float* __restrict__ ws)
{
    __shared__ float WSY_l[1024], WYY_l[1024];
    const int b = blockIdx.x;
    const int t = threadIdx.x;

    if (SLAB) {
        const int e4 = t << 2;
        const float* PS = ws + OFF_PART;
        const float* PY = ws + OFF_PART + PART_FLOATS;
        float4 a = make_float4(0.f, 0.f, 0.f, 0.f);
        float4 c = make_float4(0.f, 0.f, 0.f, 0.f);
        #pragma unroll
        for (int ch = 0; ch < NCH; ++ch) {
            const size_t o = ((size_t)(ch * 64 + b)) * 1024 + e4;
            const float4 v = *(const float4*)&PS[o];
            const float4 u = *(const float4*)&PY[o];
            a.x += v.x; a.y += v.y; a.z += v.z; a.w += v.w;
            c.x += u.x; c.y += u.y; c.z += u.z; c.w += u.w;
        }
        *(float4*)&WSY_l[e4] = a;
        *(float4*)&WYY_l[e4] = c;
    } else {
        for (int e = t; e < 1024; e += 256) {
            WSY_l[e] = ws[OFF_WSY + b * 1024 + e];
            WYY_l[e] = ws[OFF_WYY + b * 1024 + e];
        }
    }
    __syncthreads();

    if (t < 64) {
        const int lane = t;
        const int i = lane & 31;   // lanes 32..63 mirror 0..31 (writes guarded)

        float row_sy[32], col_sy[32], row_yy[32];
        #pragma unroll
        for (int j = 0; j < 32; ++j) {
            row_sy[j] = WSY_l[i * 32 + j];   // s_i . y_j
            col_sy[j] = WSY_l[j * 32 + i];   // s_j . y_i
            row_yy[j] = WYY_l[i * 32 + j];   // y_i . y_j
        }

        const double r = 1.0 / (double)row_sy[i];          // 1/(s_i.y_i)
        double acc = -(double)ws[OFF_VS + b * 32 + i];     // s_i.q0 running
        double a_val = 0.0;
        #pragma unroll
        for (int j = 31; j >= 0; --j) {                    // backward scan
            const double aj = __shfl(r, j) * __shfl(acc, j);
            if (i == j) a_val = aj;
            if (i < j)  acc -= aj * (double)row_sy[j];
        }

        const double g = (double)WSY_l[31 * 32 + 31] / (double)WYY_l[31 * 32 + 31];

        double u = -(double)ws[OFF_VY + b * 32 + i];       // y_i.q_f0 / g
        #pragma unroll
        for (int j = 0; j < 32; ++j)
            u -= __shfl(a_val, j) * (double)row_yy[j];
        u *= g;

        double tt = u;
        double b_val = 0.0;
        #pragma unroll
        for (int j = 0; j < 32; ++j) {                     // forward scan
            const double bj = __shfl(r, j) * __shfl(tt, j);
            if (i == j) b_val = bj;
            const double dj = __shfl(a_val, j) - bj;
            if (i > j) tt += dj * (double)col_sy[j];
        }

        if (lane < 32) {
            ws[OFF_CY + b * 32 + i] = (float)(g * a_val);
            ws[OFF_CS + b * 32 + i] = (float)(b_val - a_val);
        }
        if (lane == 0) ws[OFF_G + b] = (float)g;
    }
}

// ---------------------------------------------------------------------------
// Kernel C: out[b,d] = g*frc[b,d] + sum_i cy[i]*y[i,b,d] + cs[i]*s[i,b,d]
// grid = 64 b x 8 d-chunks, 1024 threads (16 waves). i-sum split 4-way
// across thread quarters, LDS tree reduce at end. (unchanged)
// ---------------------------------------------------------------------------
__global__ __launch_bounds__(1024) void combine_kernel(
    const float* __restrict__ s, const float* __restrict__ y,
    const float* __restrict__ frc, const float* __restrict__ ws,
    float* __restrict__ out)
{
    __shared__ float cy[32], cs[32];
    __shared__ float4 red[3][256];
    const int b  = blockIdx.x & 63;
    const int ch = blockIdx.x >> 6;
    const int t  = threadIdx.x;
    const int q  = t >> 8;          // quarter 0..3: i in [8q, 8q+8)
    const int tt = t & 255;
    if (t < 32) { cy[t] = ws[OFF_CY + b * 32 + t]; cs[t] = ws[OFF_CS + b * 32 + t]; }
    __syncthreads();

    const int d = ch * 1024 + (tt << 2);
    float4 acc = make_float4(0.f, 0.f, 0.f, 0.f);
    if (q == 0) {
        const float g = ws[OFF_G + b];
        const float4 fv = *(const float4*)(frc + (size_t)b * Dh + d);
        acc.x = g * fv.x; acc.y = g * fv.y; acc.z = g * fv.z; acc.w = g * fv.w;
    }
    const int ib = q << 3;
    #pragma unroll
    for (int i2 = 0; i2 < 8; ++i2) {
        const int i = ib + i2;
        const float4 yv = *(const float4*)(y + ((size_t)i * Bh + b) * Dh + d);
        const float4 sv = *(const float4*)(s + ((size_t)i * Bh + b) * Dh + d);
        const float a1 = cy[i], a2 = cs[i];
        acc.x += a1 * yv.x + a2 * sv.x;
        acc.y += a1 * yv.y + a2 * sv.y;
        acc.z += a1 * yv.z + a2 * sv.z;
        acc.w += a1 * yv.w + a2 * sv.w;
    }
    if (q) red[q - 1][tt] = acc;
    __syncthreads();
    if (q == 0) {
        const float4 r0 = red[0][tt], r1 = red[1][tt], r2 = red[2][tt];
        acc.x += r0.x + r1.x + r2.x;
        acc.y += r0.y + r1.y + r2.y;
        acc.z += r0.z + r1.z + r2.z;
        acc.w += r0.w + r1.w + r2.w;
        *(float4*)(out + (size_t)b * Dh + d) = acc;
    }
}

extern "C" void kernel_launch(void* const* d_in, const int* in_sizes, int n_in,
                              void* d_out, int out_size, void* d_ws, size_t ws_size,
                              hipStream_t stream)
{
    const float* s   = (const float*)d_in[0];
    const float* y   = (const float*)d_in[1];
    const float* frc = (const float*)d_in[2];
    float* out = (float*)d_out;
    float* ws  = (float*)d_ws;

    const size_t need = ((size_t)OFF_PART + 2 * (size_t)PART_FLOATS) * sizeof(float);
    if (ws_size >= need) {
        // slab path: only vs/vy use atomics -> zero just that 16 KB
        hipMemsetAsync((char*)d_ws + (size_t)OFF_VS * sizeof(float), 0,
                       (size_t)(OFF_CY - OFF_VS) * sizeof(float), stream);
        gram_kernel<1><<<dim3(Bh * NCH), dim3(256), 0, stream>>>(s, y, frc, ws);
        recur_kernel<1><<<dim3(Bh), dim3(256), 0, stream>>>(ws);
    } else {
        // atomic fallback
        hipMemsetAsync(d_ws, 0, (size_t)WS_ZERO_FLOATS * sizeof(float), stream);
        gram_kernel<0><<<dim3(Bh * NCH), dim3(256), 0, stream>>>(s, y, frc, ws);
        recur_kernel<0><<<dim3(Bh), dim3(256), 0, stream>>>(ws);
    }
    combine_kernel<<<dim3(Bh * CCH), dim3(1024), 0, stream>>>(s, y, frc, ws, out);
}